// Round 15
// baseline (93.411 us; speedup 1.0000x reference)
//
#include <hip/hip_runtime.h>

// RegionSelection, FULLY FUSED single kernel (r15).
// Every block redundantly computes its batch's top-k threshold from the
// attention map (25 KB, L2-resident; pure LDS/VALU, overlaps nothing it
// shouldn't), then streams its 4 assigned feature planes. No select kernel,
// no inter-kernel gap, no workspace, no cross-block communication.
// Established by A/B (r6-r14): plain LOAD (feat goes Infinity-Cache resident
// across replays; FETCH 200->102 MB measured) + NT STORE (writes stream past
// the caches). Arithmetic identical to the validated r9/r13 kernels.

#define NIN   6400    // 80*80
#define NUP   25600   // 160*160
#define KRANK 1921u   // (k+1)-th largest == topv[:, k]

typedef float f32x4 __attribute__((ext_vector_type(4)));

// Wave-parallel "find bin containing rank `rem_in` counting from the top" over
// NBINS bins. Two-level: 64 chunk sums + shfl suffix-scan, then a parallel
// scan of the selected chunk. Executed by wave 0; result -> s_bcast.
template <int NBINS>
__device__ inline void find_bin(const unsigned* s_hist, unsigned rem_in,
                                unsigned* s_bcast, int tid)
{
    constexpr int CHUNK = NBINS / 64;
    if (tid < 64) {
        const int lane = tid;
        unsigned csum = 0;
        #pragma unroll
        for (int k = 0; k < CHUNK; ++k) csum += s_hist[lane * CHUNK + k];
        unsigned suff = csum;
        #pragma unroll
        for (int off = 1; off < 64; off <<= 1) {
            unsigned o = __shfl_down(suff, off);
            if (lane + off < 64) suff += o;
        }
        unsigned suff_next = __shfl_down(suff, 1);
        if (lane == 63) suff_next = 0;
        const bool hit = (suff >= rem_in) & (suff_next < rem_in);
        unsigned long long bmask = __ballot(hit);
        const int src = (int)__builtin_ctzll(bmask);
        const unsigned r_chunk = __shfl(rem_in - suff_next, src);
        const int      cbase   = src * CHUNK;
        unsigned h = (lane < CHUNK) ? s_hist[cbase + lane] : 0u;
        unsigned ssum = h;
        #pragma unroll
        for (int off = 1; off < CHUNK; off <<= 1) {
            unsigned o = __shfl_down(ssum, off);
            if (lane + off < CHUNK) ssum += o;
        }
        unsigned ssum_next = __shfl_down(ssum, 1);
        if (lane >= CHUNK - 1) ssum_next = 0;
        const bool hit2 = (lane < CHUNK) & (ssum >= r_chunk) & (ssum_next < r_chunk);
        if (hit2) {
            s_bcast[0] = (unsigned)(cbase + lane);
            s_bcast[1] = r_chunk - ssum_next;
        }
    }
}

__global__ __launch_bounds__(1024) void fused_region_kernel(
    const float* __restrict__ att, const f32x4* __restrict__ feat,
    f32x4* __restrict__ out, f32x4* __restrict__ mask_out)
{
    __shared__ float    s_in[NIN + 81];  // +81: zero pad so y1/x1 overruns are safe
    __shared__ unsigned s_hist[2048];
    __shared__ unsigned s_bits[800];     // bit-packed mask for this batch
    __shared__ unsigned s_bcast[2];

    const int tid = threadIdx.x;
    const int bid = blockIdx.x;          // 0..511
    const int b   = bid >> 6;            // batch (64 blocks per batch)
    const int sub = bid & 63;            // 4-plane group within batch

    // ---- Phase A: stage attention map (25.6 KB, L2-resident after 1st touch)
    const float* in = att + b * NIN;
    for (int i = tid; i < NIN; i += 1024) s_in[i] = in[i];
    if (tid < 81) s_in[NIN + tid] = 0.0f;
    __syncthreads();

    // ---- Phase B: branch-free bilinear 2x upsample (r9, validated absmax==0)
    unsigned ub[25];
    #pragma unroll
    for (int j = 0; j < 25; ++j) {
        int i = j * 1024 + tid;
        int r = i / 160;
        int c = i - r * 160;
        float yf = fmaxf(0.5f * (float)r - 0.25f, 0.0f);
        int   y0 = (int)yf;
        float wy = yf - (float)y0;
        wy = (y0 >= 79) ? 0.0f : wy;
        float xf = fmaxf(0.5f * (float)c - 0.25f, 0.0f);
        int   x0 = (int)xf;
        float wx = xf - (float)x0;
        wx = (x0 >= 79) ? 0.0f : wx;
        const float* p0 = &s_in[y0 * 80 + x0];
        float a00 = p0[0], a01 = p0[1];
        float a10 = p0[80], a11 = p0[81];
        float top = a00 * (1.0f - wx) + a01 * wx;
        float bot = a10 * (1.0f - wx) + a11 * wx;
        float v   = top * (1.0f - wy) + bot * wy;
        ub[j] = __float_as_uint(v);   // v in [0,1) -> uint order == float order
    }

    // ---- Phase C: exact radix select, 3 passes (r3-r8 layout, validated)
    // bits [30:20] (2048 bins), [19:10] (1024), [9:0] (1024)
    for (int i = tid; i < 2048; i += 1024) s_hist[i] = 0;
    __syncthreads();
    #pragma unroll
    for (int j = 0; j < 25; ++j) atomicAdd(&s_hist[ub[j] >> 20], 1u);  // < 2048
    __syncthreads();
    find_bin<2048>(s_hist, KRANK, s_bcast, tid);
    __syncthreads();
    const unsigned p1  = s_bcast[0];
    unsigned       rem = s_bcast[1];
    __syncthreads();

    for (int i = tid; i < 1024; i += 1024) s_hist[i] = 0;
    __syncthreads();
    #pragma unroll
    for (int j = 0; j < 25; ++j) {
        unsigned u = ub[j];
        if ((u >> 20) == p1) atomicAdd(&s_hist[(u >> 10) & 1023u], 1u);
    }
    __syncthreads();
    find_bin<1024>(s_hist, rem, s_bcast, tid);
    __syncthreads();
    const unsigned pref2 = (p1 << 10) | s_bcast[0];   // bits [30:10]
    rem = s_bcast[1];
    __syncthreads();

    for (int i = tid; i < 1024; i += 1024) s_hist[i] = 0;
    __syncthreads();
    #pragma unroll
    for (int j = 0; j < 25; ++j) {
        unsigned u = ub[j];
        if ((u >> 10) == pref2) atomicAdd(&s_hist[u & 1023u], 1u);
    }
    __syncthreads();
    find_bin<1024>(s_hist, rem, s_bcast, tid);
    __syncthreads();
    const unsigned thr_bits = (pref2 << 10) | s_bcast[0];

    // ---- Phase D: ballot the selection bits into LDS (element e=j*1024+wv*64+lane)
    const int lane = tid & 63;
    const int wv   = tid >> 6;           // 0..15
    #pragma unroll
    for (int j = 0; j < 25; ++j) {
        unsigned long long bal = __ballot(ub[j] >= thr_bits);
        if (lane == 0) {
            s_bits[j * 32 + wv * 2]     = (unsigned)bal;
            s_bits[j * 32 + wv * 2 + 1] = (unsigned)(bal >> 32);
        }
    }
    __syncthreads();

    // ---- Phase F: stream 4 planes (25600 f32x4 contiguous chunk)
    const int base = (b * 256 + sub * 4) * 6400;      // f32x4 index, fits int32
    const f32x4* fp = feat + base + tid;
    f32x4*       op = out  + base + tid;

    f32x4 v[25];
    #pragma unroll
    for (int q = 0; q < 25; ++q)
        v[q] = fp[q * 1024];                           // plain load (L3 allocate)

    #pragma unroll
    for (int q = 0; q < 25; ++q) {
        const int idx = q * 1024 + tid;                // 0..25599 in 4-plane chunk
        const int u   = idx - (idx / 6400) * 6400;     // f32x4 index within plane
        const unsigned nib = s_bits[u >> 3] >> ((u & 7) * 4);
        f32x4 w;
        w.x = (nib & 1u) ? 1.1f : 0.1f;   // 1.0f+0.1f == 1.1f bitwise (0x3F8CCCCD)
        w.y = (nib & 2u) ? 1.1f : 0.1f;
        w.z = (nib & 4u) ? 1.1f : 0.1f;
        w.w = (nib & 8u) ? 1.1f : 0.1f;
        __builtin_nontemporal_store(v[q] * w, op + q * 1024);
    }

    // ---- Phase G: fp32 mask slice (64 blocks x 100 f32x4 cover the plane)
    if (tid < 100) {
        const unsigned um  = (unsigned)(sub * 100 + tid);
        const unsigned nib = s_bits[um >> 3] >> ((um & 7u) * 4u);
        f32x4 w;
        w.x = (nib & 1u) ? 1.0f : 0.0f;
        w.y = (nib & 2u) ? 1.0f : 0.0f;
        w.z = (nib & 4u) ? 1.0f : 0.0f;
        w.w = (nib & 8u) ? 1.0f : 0.0f;
        mask_out[b * 6400 + um] = w;
    }
}

extern "C" void kernel_launch(void* const* d_in, const int* in_sizes, int n_in,
                              void* d_out, int out_size, void* d_ws, size_t ws_size,
                              hipStream_t stream)
{
    const float* local_feat = (const float*)d_in[0];   // (8,256,160,160) fp32
    const float* att        = (const float*)d_in[1];   // (8,1,80,80) fp32
    // d_in[2] = spatial_scale (==2, fixed by problem shapes)

    float* out      = (float*)d_out;
    float* mask_out = out + 8 * 256 * 160 * 160;       // second output region

    fused_region_kernel<<<512, 1024, 0, stream>>>(
        att, (const f32x4*)local_feat, (f32x4*)out, (f32x4*)mask_out);
}

// Round 16
// 85.406 us; speedup vs baseline: 1.0937x; 1.0937x over previous
//
#include <hip/hip_runtime.h>

// RegionSelection: bilinear 2x upsample of attention map (8,1,80,80)->(8,1,160,160),
// per-batch rank-1921 threshold (k=int(0.3*6400)=1920, threshold=topv[:,k]),
// mask = up >= thr, weighted = local_feat*(mask+0.1).
// Outputs concatenated: weighted (8*256*160*160 fp32) then mask (8*160*160 fp32).
// d_ws: bit-packed mask, 400 ull per batch.
//
// FINAL CONFIG (best measured, r13 = 85.3 us). Established by A/B r6-r15:
//  - plain LOAD: feat (200MB < 256MB L3) goes Infinity-Cache resident across
//    graph replays; measured FETCH 200->102.5 MB. (nt-load forfeits this.)
//  - NT STORE: writes stream past L3, keeping it for the read stream.
//    (plain stores thrash L3: r8 = 121.6 us.)
//  - full 25-deep unroll: MLP to cover load latency (r10: -10 us).
//  - 2-kernel split: redundant-select fusion regressed (r15: +8 us,
//    37KB LDS -> 2 blocks/CU, 2.1M bank conflicts, serial select prologue).

#define NIN   6400    // 80*80
#define NUP   25600   // 160*160
#define KRANK 1921u   // (k+1)-th largest == topv[:, k]

typedef float f32x4 __attribute__((ext_vector_type(4)));

// Wave-parallel "find bin containing rank `rem_in` counting from the top" over
// NBINS bins. Two-level: 64 chunk sums + shfl suffix-scan, then a parallel
// scan of the selected chunk. Executed by wave 0; result -> s_bcast.
template <int NBINS>
__device__ inline void find_bin(const unsigned* s_hist, unsigned rem_in,
                                unsigned* s_bcast, int tid)
{
    constexpr int CHUNK = NBINS / 64;
    if (tid < 64) {
        const int lane = tid;
        unsigned csum = 0;
        #pragma unroll
        for (int k = 0; k < CHUNK; ++k) csum += s_hist[lane * CHUNK + k];
        unsigned suff = csum;
        #pragma unroll
        for (int off = 1; off < 64; off <<= 1) {
            unsigned o = __shfl_down(suff, off);
            if (lane + off < 64) suff += o;
        }
        unsigned suff_next = __shfl_down(suff, 1);
        if (lane == 63) suff_next = 0;
        const bool hit = (suff >= rem_in) & (suff_next < rem_in);
        unsigned long long bmask = __ballot(hit);
        const int src = (int)__builtin_ctzll(bmask);
        const unsigned r_chunk = __shfl(rem_in - suff_next, src);
        const int      cbase   = src * CHUNK;
        unsigned h = (lane < CHUNK) ? s_hist[cbase + lane] : 0u;
        unsigned ssum = h;
        #pragma unroll
        for (int off = 1; off < CHUNK; off <<= 1) {
            unsigned o = __shfl_down(ssum, off);
            if (lane + off < CHUNK) ssum += o;
        }
        unsigned ssum_next = __shfl_down(ssum, 1);
        if (lane >= CHUNK - 1) ssum_next = 0;
        const bool hit2 = (lane < CHUNK) & (ssum >= r_chunk) & (ssum_next < r_chunk);
        if (hit2) {
            s_bcast[0] = (unsigned)(cbase + lane);
            s_bcast[1] = r_chunk - ssum_next;
        }
    }
}

// Same, over the SUM of two 4096-bin sub-histograms (wave-parity split).
__device__ inline void find_bin_4096x2(const unsigned* h0, const unsigned* h1,
                                       unsigned rem_in, unsigned* s_bcast, int tid)
{
    if (tid < 64) {
        const int lane = tid;
        unsigned csum = 0;
        #pragma unroll
        for (int k = 0; k < 64; ++k) {
            const int idx = lane * 64 + k;
            csum += h0[idx] + h1[idx];
        }
        unsigned suff = csum;
        #pragma unroll
        for (int off = 1; off < 64; off <<= 1) {
            unsigned o = __shfl_down(suff, off);
            if (lane + off < 64) suff += o;
        }
        unsigned suff_next = __shfl_down(suff, 1);
        if (lane == 63) suff_next = 0;
        const bool hit = (suff >= rem_in) & (suff_next < rem_in);
        unsigned long long bmask = __ballot(hit);
        const int src = (int)__builtin_ctzll(bmask);
        const unsigned r_chunk = __shfl(rem_in - suff_next, src);
        const int      cbase   = src * 64;
        unsigned hsum = h0[cbase + lane] + h1[cbase + lane];
        unsigned ssum = hsum;
        #pragma unroll
        for (int off = 1; off < 64; off <<= 1) {
            unsigned o = __shfl_down(ssum, off);
            if (lane + off < 64) ssum += o;
        }
        unsigned ssum_next = __shfl_down(ssum, 1);
        if (lane == 63) ssum_next = 0;
        const bool hit2 = (ssum >= r_chunk) & (ssum_next < r_chunk);
        if (hit2) {
            s_bcast[0] = (unsigned)(cbase + lane);
            s_bcast[1] = r_chunk - ssum_next;
        }
    }
}

__global__ __launch_bounds__(1024) void upsample_select_kernel(
    const float* __restrict__ att, unsigned long long* __restrict__ ws_bits)
{
    __shared__ float    s_in[NIN + 81];  // +81: zero pad so y1/x1 overruns are safe
    __shared__ unsigned s_hist[8192];    // 2 x 4096 sub-histograms (pass 1)
    __shared__ unsigned s_bcast[2];

    const int b   = blockIdx.x;
    const int tid = threadIdx.x;

    const float* in = att + b * NIN;
    for (int i = tid; i < NIN; i += 1024) s_in[i] = in[i];
    if (tid < 81) s_in[NIN + tid] = 0.0f;
    __syncthreads();

    // Branch-free bilinear 2x upsample, half-pixel centers. Edge clamping via
    // fmaxf (low edge) and wy/wx := 0 at the high edge; out-of-row/pad reads
    // are multiplied by exactly 0.0f -> results bit-identical to the
    // branchy version validated in rounds 1-9 (absmax==0).
    unsigned ub[25];
    #pragma unroll
    for (int j = 0; j < 25; ++j) {
        int i = j * 1024 + tid;
        int r = i / 160;
        int c = i - r * 160;
        float yf = fmaxf(0.5f * (float)r - 0.25f, 0.0f);
        int   y0 = (int)yf;
        float wy = yf - (float)y0;
        wy = (y0 >= 79) ? 0.0f : wy;
        float xf = fmaxf(0.5f * (float)c - 0.25f, 0.0f);
        int   x0 = (int)xf;
        float wx = xf - (float)x0;
        wx = (x0 >= 79) ? 0.0f : wx;
        const float* p0 = &s_in[y0 * 80 + x0];
        float a00 = p0[0], a01 = p0[1];        // merge -> ds_read2_b32
        float a10 = p0[80], a11 = p0[81];
        float top = a00 * (1.0f - wx) + a01 * wx;
        float bot = a10 * (1.0f - wx) + a11 * wx;
        float v   = top * (1.0f - wy) + bot * wy;
        ub[j] = __float_as_uint(v);   // v in [0,1) -> uint order == float order
    }

    // ---- exact radix select, 3 passes: bits [30:19], [18:9], [8:0] ----
    unsigned* myh = s_hist + ((tid >> 6) & 1) * 4096;
    for (int i = tid; i < 8192; i += 1024) s_hist[i] = 0;
    __syncthreads();
    #pragma unroll
    for (int j = 0; j < 25; ++j) atomicAdd(&myh[ub[j] >> 19], 1u);  // < 4096
    __syncthreads();
    find_bin_4096x2(s_hist, s_hist + 4096, KRANK, s_bcast, tid);
    __syncthreads();
    const unsigned p1  = s_bcast[0];
    unsigned       rem = s_bcast[1];
    __syncthreads();

    for (int i = tid; i < 1024; i += 1024) s_hist[i] = 0;
    __syncthreads();
    #pragma unroll
    for (int j = 0; j < 25; ++j) {
        unsigned u = ub[j];
        if ((u >> 19) == p1) atomicAdd(&s_hist[(u >> 9) & 1023u], 1u);
    }
    __syncthreads();
    find_bin<1024>(s_hist, rem, s_bcast, tid);
    __syncthreads();
    const unsigned pref2 = (p1 << 10) | s_bcast[0];    // bits [30:9]
    rem = s_bcast[1];
    __syncthreads();

    for (int i = tid; i < 512; i += 1024) s_hist[i] = 0;
    __syncthreads();
    #pragma unroll
    for (int j = 0; j < 25; ++j) {
        unsigned u = ub[j];
        if ((u >> 9) == pref2) atomicAdd(&s_hist[u & 511u], 1u);
    }
    __syncthreads();
    find_bin<512>(s_hist, rem, s_bcast, tid);
    __syncthreads();
    const unsigned thr_bits = (pref2 << 9) | s_bcast[0];

    // Output: ONLY the bit-packed mask (3.2 KB/batch).
    unsigned long long* wbptr = ws_bits + b * 400;   // 400 ull = 25600 bits
    const int lane = tid & 63;
    const int wv   = tid >> 6;
    #pragma unroll
    for (int j = 0; j < 25; ++j) {
        unsigned long long bal = __ballot(ub[j] >= thr_bits);  // bit i = elem j*1024+wv*64+i
        if (lane == 0) wbptr[j * 16 + wv] = bal;
    }
}

// weighted = local_feat * (mask + 0.1), plus mask fp32 materialization.
// One block per (b,c) plane; bit-packed mask in LDS (3.2 KB); full unroll
// (25-deep MLP, r10). PLAIN loads (Infinity-Cache residency across replays)
// + NT stores (stream past the caches). Best measured cell: 85.3 us (r13).
__global__ __launch_bounds__(256) void apply_mask_kernel(
    const f32x4* __restrict__ feat, const unsigned* __restrict__ bits,
    f32x4* __restrict__ out, f32x4* __restrict__ mask_out)
{
    __shared__ unsigned s_bits[800];

    const int tid   = threadIdx.x;
    const int plane = blockIdx.x;          // b*256 + c
    const int b     = plane >> 8;
    const int c     = plane & 255;

    const unsigned* gb = bits + b * 800;
    #pragma unroll
    for (int k = 0; k < 3; ++k) s_bits[tid + k * 256] = gb[tid + k * 256];
    if (tid < 32) s_bits[768 + tid] = gb[768 + tid];
    __syncthreads();

    const f32x4* fp = feat + plane * 6400 + tid;
    f32x4*       op = out  + plane * 6400 + tid;

    f32x4 v[25];
    #pragma unroll
    for (int i = 0; i < 25; ++i)
        v[i] = fp[i * 256];                        // PLAIN load (L2/L3 allocate)

    #pragma unroll
    for (int i = 0; i < 25; ++i) {
        const unsigned u   = (unsigned)(i * 256 + tid);        // f32x4 index in plane
        const unsigned nib = s_bits[u >> 3] >> ((u & 7u) * 4u);
        f32x4 w;
        w.x = (nib & 1u) ? 1.1f : 0.1f;   // 1.0f+0.1f == 1.1f bitwise (0x3F8CCCCD)
        w.y = (nib & 2u) ? 1.1f : 0.1f;
        w.z = (nib & 4u) ? 1.1f : 0.1f;
        w.w = (nib & 8u) ? 1.1f : 0.1f;
        __builtin_nontemporal_store(v[i] * w, op + i * 256);   // NT store
    }

    // epilogue: first 8 channel-blocks of each batch emit the fp32 mask plane
    // (800 f32x4 segment each) straight from the bits already in LDS.
    if (c < 8) {
        f32x4* mop = mask_out + b * 6400 + c * 800;
        #pragma unroll
        for (int t = 0; t < 4; ++t) {
            int k = t * 256 + tid;
            if (k < 800) {
                const unsigned nib = s_bits[(c * 800 + k) >> 3] >> (((c * 800 + k) & 7u) * 4u);
                f32x4 w;
                w.x = (nib & 1u) ? 1.0f : 0.0f;
                w.y = (nib & 2u) ? 1.0f : 0.0f;
                w.z = (nib & 4u) ? 1.0f : 0.0f;
                w.w = (nib & 8u) ? 1.0f : 0.0f;
                mop[k] = w;
            }
        }
    }
}

extern "C" void kernel_launch(void* const* d_in, const int* in_sizes, int n_in,
                              void* d_out, int out_size, void* d_ws, size_t ws_size,
                              hipStream_t stream)
{
    const float* local_feat = (const float*)d_in[0];   // (8,256,160,160) fp32
    const float* att        = (const float*)d_in[1];   // (8,1,80,80) fp32
    // d_in[2] = spatial_scale (==2, fixed by problem shapes)

    float* out      = (float*)d_out;
    float* mask_out = out + 8 * 256 * 160 * 160;       // second output region

    upsample_select_kernel<<<8, 1024, 0, stream>>>(
        att, (unsigned long long*)d_ws);

    apply_mask_kernel<<<2048, 256, 0, stream>>>(
        (const f32x4*)local_feat, (const unsigned*)d_ws,
        (f32x4*)out, (f32x4*)mask_out);
}